// Round 15
// baseline (109.913 us; speedup 1.0000x reference)
//
#include <hip/hip_runtime.h>

// Light-field per-pixel 9x9 filter, R15.
// out[b,s,o,h,w] = clip(sum_{i,ky,kx} lf[b,s,i,3h-3+ky,3w-3+kx] * W[s,o,i,h,w,81] + bias, 0, 1)
//
// R14 post-mortem: multi-change sync restructure failed correctness; reverted
// to R11's proven schedule. R15 = R11 with WQ=8: weight LDS 7.8 KB -> 16
// blocks/CU = 32 waves/CU (vs R11's 20), same single-buffer stage->drain->
// compute barriers. ky split 4-way over lane groups; XCD-chunked bijective
// block swizzle (18432 = 8 x 2304) for lf L2 locality.

#define ST 9
#define INC 3
#define OUTC 3
#define OHH 128
#define OWW 128
#define KDIM 9
#define KK 81
#define HH 384
#define WW 384
#define HWSZ (HH*WW)          // 147456
#define WQ 8                  // w columns per block
#define SLICE (WQ*KK)         // 648 floats = 2592 B per (s,o,i,h,w-8th)
#define NWG (ST*OHH*16)       // 18432 blocks

typedef float f32x4 __attribute__((ext_vector_type(4)));
struct __attribute__((packed, aligned(4))) U4 { f32x4 v; };  // align-4 vector load

__device__ __forceinline__ void gll16(const float* g, float* l) {
  __builtin_amdgcn_global_load_lds((const __attribute__((address_space(1))) void*)g,
                                   (__attribute__((address_space(3))) void*)l, 16, 0, 0);
}

__global__ __launch_bounds__(128) void lf_filter_kernel(
    const float* __restrict__ lf, const float* __restrict__ wts,
    const float* __restrict__ bias, float* __restrict__ out)
{
  __shared__ __align__(16) float ldsW[OUTC][SLICE];   // 7776 B -> 16 blocks/CU

  const int t   = threadIdx.x;
  const int wl  = t & 7;           // w within group
  const int b   = (t >> 3) & 3;    // batch
  const int kq  = t >> 5;          // ky quarter (lane-group)
  const int raw = blockIdx.x;
  const int bid = (raw & 7) * (NWG/8) + (raw >> 3);   // XCD-chunked bijective swizzle
  const int wg  = bid & 15;        // w group of 8
  const int h   = (bid >> 4) & 127;
  const int s   = bid >> 11;
  const int w   = wg*WQ + wl;
  const int xbase = 3*w - 3;
  const int ybase = 3*h - 3;

  // clamped vector-load base + edge shift (nonzero only for w=0 / w=127)
  const int  base  = xbase < 0 ? 0 : (xbase > WW-KDIM ? WW-KDIM : xbase);
  const bool s_neg = (xbase < base);
  const bool s_pos = (xbase > base);

  const float* lfb = lf + (size_t)(b*ST + s)*INC*HWSZ;
  const int wu = (t & ~63) * 4;    // wave-uniform LDS dest float offset

  const int kyA = kq*2;
  const int nky = (kq == 3) ? 3 : 2;   // rows {0,1},{2,3},{4,5},{6,7,8}

  float acc[OUTC] = {0.f, 0.f, 0.f};

  #pragma unroll 1
  for (int i = 0; i < INC; ++i) {
    __syncthreads();   // all waves done reading ldsW from previous i

    // ---- stage the 3 o-slices (162 float4 chunks each) ----
    #pragma unroll
    for (int o = 0; o < OUTC; ++o) {
      const float* wsrc = wts + ((size_t)(((s*OUTC + o)*INC + i)*OHH + h)*OWW + wg*WQ)*KK;
      float* dst = ldsW[o];
      gll16(wsrc + (size_t)t*4, dst + wu);             // chunks 0..127
      if (t < 34)                                      // tail chunks 128..161
        gll16(wsrc + (size_t)(128 + t)*4, dst + 512 + wu);
    }
    __syncthreads();   // drain vmcnt: all 3 slices landed

    // ---- compute this lane-group's ky rows; lf row reused across 3 o's ----
    const float* lfr = lfb + (size_t)i*HWSZ;
    const int wb = wl*KK;
    #pragma unroll 1
    for (int r = 0; r < nky; ++r) {
      const int ky = kyA + r;
      const int y  = ybase + ky;
      if ((unsigned)y < (unsigned)HH) {    // predicated (lane-group divergent)
        const float* rp = lfr + (size_t)y*WW + base;
        const f32x4 va = reinterpret_cast<const U4*>(rp)->v;
        const f32x4 vb = reinterpret_cast<const U4*>(rp + 4)->v;
        const float rc = rp[8];
        const float raw9[KDIM] = {va.x, va.y, va.z, va.w, vb.x, vb.y, vb.z, vb.w, rc};
        float lv[KDIM];
        #pragma unroll
        for (int kx = 0; kx < KDIM; ++kx) {
          const float nv = (kx >= 3) ? raw9[kx-3] : 0.f;
          const float pv = (kx <= 5) ? raw9[kx+3] : 0.f;
          lv[kx] = s_neg ? nv : (s_pos ? pv : raw9[kx]);
        }
        const int kb = wb + ky*KDIM;
        #pragma unroll
        for (int o = 0; o < OUTC; ++o) {
          const float* wrow = &ldsW[o][kb];   // 17*wl (+9ky split) mod 32: conflict-free
          float a = acc[o];
          #pragma unroll
          for (int kx = 0; kx < KDIM; ++kx)
            a = fmaf(lv[kx], wrow[kx], a);
          acc[o] = a;
        }
      }
    }
  }

  // ---- combine ky-quarters via LDS (reuse ldsW), epilogue by kq=0 ----
  float* part = (float*)ldsW;       // 3 groups x 32 x 3 = 288 floats
  __syncthreads();                  // everyone done reading weights
  if (kq != 0) {
    const int q = t & 31;           // == b*WQ + wl
    #pragma unroll
    for (int o = 0; o < OUTC; ++o) part[(kq-1)*96 + q*3 + o] = acc[o];
  }
  __syncthreads();
  if (kq == 0) {
    #pragma unroll
    for (int o = 0; o < OUTC; ++o) {
      const float bv = bias[((s*OUTC + o)*OHH + h)*OWW + w];
      float r = acc[o] + part[t*3 + o] + part[96 + t*3 + o] + part[192 + t*3 + o] + bv;
      r = r < 0.f ? 0.f : (r > 1.f ? 1.f : r);
      out[(((size_t)(b*ST + s)*OUTC + o)*OHH + h)*OWW + w] = r;
    }
  }
}

extern "C" void kernel_launch(void* const* d_in, const int* in_sizes, int n_in,
                              void* d_out, int out_size, void* d_ws, size_t ws_size,
                              hipStream_t stream) {
  const float* lf   = (const float*)d_in[0];
  const float* wts  = (const float*)d_in[1];
  const float* bias = (const float*)d_in[2];
  float* out = (float*)d_out;
  dim3 grid(NWG);     // 18432 blocks: (s, h, w-group), XCD-swizzled
  dim3 block(128);    // (w:8) x (batch:4) x (ky-quarter:4)
  hipLaunchKernelGGL(lf_filter_kernel, grid, block, 0, stream, lf, wts, bias, out);
}